// Round 8
// baseline (215.572 us; speedup 1.0000x reference)
//
#include <hip/hip_runtime.h>
#include <math.h>

#define DD 128          // embed dim
#define DEG 16          // neighbors
#define TM 16           // node tile per block (grid = 50000/16 = 3125 exactly)
#define EPSV 1e-5f

typedef _Float16 half8_t __attribute__((ext_vector_type(8)));
typedef float    f32x4   __attribute__((ext_vector_type(4)));
typedef signed char c16v __attribute__((ext_vector_type(16)));
typedef signed char c8v  __attribute__((ext_vector_type(8)));

// fast tanh(n)/n, n >= EPSV.
__device__ __forceinline__ float fast_tanh_over(float n) {
    float e  = __expf(2.f * n);
    float th = 1.f - __fdividef(2.f, e + 1.f);
    return __fdividef(th, n);
}
// fast atanh(n)/n, n in [EPSV, 1-EPSV]
__device__ __forceinline__ float fast_atanh_over(float n) {
    float r = 0.5f * __logf(__fdividef(1.f + n, 1.f - n));
    return __fdividef(r, n);
}

// ---- prep: per-ROW int8 quant of x*mask^2, plus W->f16 transpose (as R7).
__global__ void prep(const float* __restrict__ x, const float* __restrict__ mask,
                     signed char* __restrict__ x8, float* __restrict__ xsc, int nA,
                     const float* __restrict__ Wp, const float* __restrict__ Wn,
                     _Float16* __restrict__ WT)
{
    if ((int)blockIdx.x < nA) {
        const int r   = blockIdx.x * 16 + (threadIdx.x >> 4);
        const int c16 = threadIdx.x & 15;
        float m  = mask[r];
        float m2 = m * m;
        const float4* xp = (const float4*)(x + (size_t)r * DD + c16 * 8);
        float4 a = xp[0], b = xp[1];
        float v[8] = {a.x*m2, a.y*m2, a.z*m2, a.w*m2, b.x*m2, b.y*m2, b.z*m2, b.w*m2};
        float mx = 0.f;
        #pragma unroll
        for (int c = 0; c < 8; ++c) mx = fmaxf(mx, fabsf(v[c]));
        mx = fmaxf(mx, __shfl_xor(mx, 1));
        mx = fmaxf(mx, __shfl_xor(mx, 2));
        mx = fmaxf(mx, __shfl_xor(mx, 4));
        mx = fmaxf(mx, __shfl_xor(mx, 8));
        float qs = __fdividef(127.f, fmaxf(mx, 1e-20f));
        int q[8];
        #pragma unroll
        for (int c = 0; c < 8; ++c) q[c] = __float2int_rn(v[c] * qs);
        unsigned lo = (q[0]&255) | ((q[1]&255)<<8) | ((q[2]&255)<<16) | ((unsigned)(q[3]&255)<<24);
        unsigned hi = (q[4]&255) | ((q[5]&255)<<8) | ((q[6]&255)<<16) | ((unsigned)(q[7]&255)<<24);
        *(uint2*)(x8 + (size_t)r * DD + c16 * 8) = make_uint2(lo, hi);
        if (c16 == 0) xsc[r] = mx * (1.f / 127.f);
    } else {
        int bid   = blockIdx.x - nA;
        int mat   = bid >> 3;              // 0..3: [l0p, l0n, l1p, l1n]
        int chunk = bid & 7;
        int l = mat >> 1, rel = mat & 1;
        const float* __restrict__ src = (rel ? Wn : Wp) + (size_t)l * DD * DD;
        _Float16* __restrict__ dst = WT + (size_t)mat * DD * DD;
        for (int o = chunk * 2048 + threadIdx.x; o < chunk * 2048 + 2048; o += 256) {
            int nn = o >> 7, kk = o & 127;
            dst[o] = (_Float16)src[kk * DD + nn];   // WT[n][k] (transposed)
        }
    }
}

// ---- K_gather: gather+aggregate ONLY. R0-R7 showed per-layer time invariant
// to ILP/bytes/lines/instructions inside the monolithic kernel; clean-build
// occupancy never exceeded ~35% (9 waves/CU) and the barrier-coupled phases
// serialize into a ~10us wave critical path. This kernel strips MFMA/epilogue:
// 2KB LDS, one barrier, (256,4) -> no spill, target 16-24 waves/CU. Aggregate
// is re-quantized per-row to int8 so both layers' agg fits the proven ws size.
__global__ __launch_bounds__(256, 4) void gather_agg(
    const signed char* __restrict__ src8,        // int8, per-row scaled
    const float* __restrict__ sscale,            // per-row scale (rowmax/127)
    const int*   __restrict__ adj, const float* __restrict__ wgt,
    signed char* __restrict__ aggP8, signed char* __restrict__ aggN8,
    float* __restrict__ ascP, float* __restrict__ ascN, int n)
{
    __shared__ int   eidxS[TM][DEG];             // 1 KB
    __shared__ float ewgtS[TM][DEG];             // 1 KB (weight * src row-scale)

    const int row0 = blockIdx.x * TM;
    const int tid  = threadIdx.x;

    // stage adjacency + folded weights (1 dword/thread + 1 scattered scale)
    {
        const int nd = tid >> 4, eg = tid & 15;
        int   av = adj[(size_t)(row0 + nd) * DEG + eg];
        float wv = wgt[(size_t)(row0 + nd) * DEG + eg];
        eidxS[nd][eg] = av;
        ewgtS[nd][eg] = wv * sscale[av];         // sign preserved
    }
    __syncthreads();

    const int l64  = tid & 63;
    const int node = (tid >> 6) * 4 + (l64 >> 4);   // 4 nodes per wave
    const int e    = (l64 >> 3) & 1;                // edge parity
    const int g    = l64 & 7;                       // 16-byte column group

    int   idxl[8];
    float wl[8];
    #pragma unroll
    for (int j = 0; j < 8; ++j) {
        idxl[j] = eidxS[node][2 * j + e];
        wl[j]   = ewgtS[node][2 * j + e];
    }

    float aP[16], aN[16];
    #pragma unroll
    for (int c = 0; c < 16; ++c) { aP[c] = 0.f; aN[c] = 0.f; }
    const signed char* __restrict__ srcg = src8 + g * 16;
    #pragma unroll
    for (int j = 0; j < 8; ++j) {
        c16v v = *(const c16v*)(srcg + ((size_t)idxl[j] << 7));
        float wp = fmaxf(wl[j], 0.f);
        float wn = fmaxf(-wl[j], 0.f);
        #pragma unroll
        for (int c = 0; c < 16; ++c) {
            float f = (float)v[c];
            aP[c] += wp * f;
            aN[c] += wn * f;
        }
    }
    // parity merge (R7-verified): keep own half, send the opposite half
    float fP[8], fN[8];
    #pragma unroll
    for (int c = 0; c < 8; ++c) {
        float ownP  = e ? aP[8 + c] : aP[c];
        float sendP = e ? aP[c]     : aP[8 + c];
        float ownN  = e ? aN[8 + c] : aN[c];
        float sendN = e ? aN[c]     : aN[8 + c];
        fP[c] = ownP + __shfl_xor(sendP, 8);
        fN[c] = ownN + __shfl_xor(sendN, 8);
    }
    // per-node row max across the 16-lane node group (bits 0..3 of l64)
    float mP = 0.f, mN = 0.f;
    #pragma unroll
    for (int c = 0; c < 8; ++c) { mP = fmaxf(mP, fabsf(fP[c])); mN = fmaxf(mN, fabsf(fN[c])); }
    mP = fmaxf(mP, __shfl_xor(mP, 1)); mN = fmaxf(mN, __shfl_xor(mN, 1));
    mP = fmaxf(mP, __shfl_xor(mP, 2)); mN = fmaxf(mN, __shfl_xor(mN, 2));
    mP = fmaxf(mP, __shfl_xor(mP, 4)); mN = fmaxf(mN, __shfl_xor(mN, 4));
    mP = fmaxf(mP, __shfl_xor(mP, 8)); mN = fmaxf(mN, __shfl_xor(mN, 8));

    float qsP = __fdividef(127.f, fmaxf(mP, 1e-20f));
    float qsN = __fdividef(127.f, fmaxf(mN, 1e-20f));
    int qp[8], qn[8];
    #pragma unroll
    for (int c = 0; c < 8; ++c) {
        qp[c] = __float2int_rn(fP[c] * qsP);
        qn[c] = __float2int_rn(fN[c] * qsN);
    }
    unsigned pl = (qp[0]&255) | ((qp[1]&255)<<8) | ((qp[2]&255)<<16) | ((unsigned)(qp[3]&255)<<24);
    unsigned ph = (qp[4]&255) | ((qp[5]&255)<<8) | ((qp[6]&255)<<16) | ((unsigned)(qp[7]&255)<<24);
    unsigned nl = (qn[0]&255) | ((qn[1]&255)<<8) | ((qn[2]&255)<<16) | ((unsigned)(qn[3]&255)<<24);
    unsigned nh = (qn[4]&255) | ((qn[5]&255)<<8) | ((qn[6]&255)<<16) | ((unsigned)(qn[7]&255)<<24);
    const size_t ob = (size_t)(row0 + node) * DD + g * 16 + e * 8;
    *(uint2*)(aggP8 + ob) = make_uint2(pl, ph);
    *(uint2*)(aggN8 + ob) = make_uint2(nl, nh);
    if ((l64 & 15) == 0) {
        ascP[row0 + node] = mP * (1.f / 127.f);
        ascN[row0 + node] = mN * (1.f / 127.f);
    }
}

// ---- K_gemm: dense dequant + MFMA + epilogue. All reads sequential/dense.
__global__ __launch_bounds__(256, 2) void gemm_ep(
    const signed char* __restrict__ aggP8, const signed char* __restrict__ aggN8,
    const float* __restrict__ ascP, const float* __restrict__ ascN,
    const float* __restrict__ mask,
    const _Float16* __restrict__ WTp, const _Float16* __restrict__ WTn,
    float* __restrict__ dst_f32,
    signed char* __restrict__ dst8, float* __restrict__ dst_scale,
    int n, int apply_logmap)
{
    __shared__ float partA[4][TM];
    __shared__ float partB[4][TM];
    __shared__ float partC[4][TM];

    const int row0 = blockIdx.x * TM;
    const int tid  = threadIdx.x;
    const int wv2  = tid >> 6;       // wave 0..3
    const int l64  = tid & 63;
    const int l15  = l64 & 15;
    const int quad = l64 >> 4;

    // A fragments: row (row0+l15), dequant by that row's scale
    const float sP = ascP[row0 + l15];
    const float sN = ascN[row0 + l15];
    half8_t aPf[4], aNf[4];
    #pragma unroll
    for (int kb = 0; kb < 4; ++kb) {
        c8v qp = *(const c8v*)(aggP8 + (size_t)(row0 + l15) * DD + kb * 32 + quad * 8);
        c8v qn = *(const c8v*)(aggN8 + (size_t)(row0 + l15) * DD + kb * 32 + quad * 8);
        #pragma unroll
        for (int c = 0; c < 8; ++c) {
            aPf[kb][c] = (_Float16)((float)qp[c] * sP);
            aNf[kb][c] = (_Float16)((float)qn[c] * sN);
        }
    }

    f32x4 acc[2];
    acc[0] = (f32x4){0.f, 0.f, 0.f, 0.f};
    acc[1] = (f32x4){0.f, 0.f, 0.f, 0.f};
    #pragma unroll
    for (int t = 0; t < 2; ++t) {
        const int nb = wv2 * 2 + t;
        const _Float16* bp = WTp + (size_t)(nb * 16 + l15) * DD + quad * 8;
        const _Float16* bn = WTn + (size_t)(nb * 16 + l15) * DD + quad * 8;
        #pragma unroll
        for (int kb = 0; kb < 4; ++kb) {
            acc[t] = __builtin_amdgcn_mfma_f32_16x16x32_f16(
                aPf[kb], *(const half8_t*)(bp + kb * 32), acc[t], 0, 0, 0);
            acc[t] = __builtin_amdgcn_mfma_f32_16x16x32_f16(
                aNf[kb], *(const half8_t*)(bn + kb * 32), acc[t], 0, 0, 0);
        }
    }

    // epilogue. C/D: row=quad*4+r, cols wv2*32 + {l15, 16+l15}
    float cv0[4], cv1[4], mr[4];
    #pragma unroll
    for (int r = 0; r < 4; ++r) {
        const int rl  = quad * 4 + r;
        const int row = row0 + rl;
        float m = (row < n) ? mask[row] : 0.f;
        mr[r] = m;
        float c0 = acc[0][r] * m, c1 = acc[1][r] * m;
        cv0[r] = c0; cv1[r] = c1;
        float p = c0 * c0 + c1 * c1;
        p += __shfl_xor(p, 1); p += __shfl_xor(p, 2);
        p += __shfl_xor(p, 4); p += __shfl_xor(p, 8);
        if (l15 == 0) partA[wv2][rl] = p;
    }
    __syncthreads();

    float x0[4], x1[4];
    #pragma unroll
    for (int r = 0; r < 4; ++r) {
        const int rl = quad * 4 + r;
        float c2 = partA[0][rl] + partA[1][rl] + partA[2][rl] + partA[3][rl];
        float nc = fmaxf(sqrtf(c2), EPSV);
        float sc = fast_tanh_over(nc);
        float m  = mr[r];
        float t0 = fmaxf(cv0[r] * sc * m, 0.f) * m;      // expmap*m, relu, *m
        float t1 = fmaxf(cv1[r] * sc * m, 0.f) * m;
        x0[r] = t0; x1[r] = t1;
        if (apply_logmap) {
            float p = t0 * t0 + t1 * t1;
            p += __shfl_xor(p, 1); p += __shfl_xor(p, 2);
            p += __shfl_xor(p, 4); p += __shfl_xor(p, 8);
            if (l15 == 0) partB[wv2][rl] = p;
        }
    }

    if (apply_logmap) {
        __syncthreads();
        float y0r[4], y1r[4];
        #pragma unroll
        for (int r = 0; r < 4; ++r) {
            const int rl = quad * 4 + r;
            float s2  = partB[0][rl] + partB[1][rl] + partB[2][rl] + partB[3][rl];
            float nc2 = fminf(fmaxf(sqrtf(s2), EPSV), 1.f - EPSV);
            float f = fast_atanh_over(nc2) * mr[r] * mr[r];
            float y0 = x0[r] * f, y1 = x1[r] * f;
            y0r[r] = y0; y1r[r] = y1;
            float mm = fmaxf(fabsf(y0), fabsf(y1));
            mm = fmaxf(mm, __shfl_xor(mm, 1));
            mm = fmaxf(mm, __shfl_xor(mm, 2));
            mm = fmaxf(mm, __shfl_xor(mm, 4));
            mm = fmaxf(mm, __shfl_xor(mm, 8));
            if (l15 == 0) partC[wv2][rl] = mm;
        }
        __syncthreads();
        #pragma unroll
        for (int r = 0; r < 4; ++r) {
            const int rl  = quad * 4 + r;
            const int row = row0 + rl;
            if (row >= n) continue;
            float rmax = fmaxf(fmaxf(partC[0][rl], partC[1][rl]),
                               fmaxf(partC[2][rl], partC[3][rl]));
            float qs = __fdividef(127.f, fmaxf(rmax, 1e-20f));
            int q0 = __float2int_rn(y0r[r] * qs);
            int q1 = __float2int_rn(y1r[r] * qs);
            signed char* drow = dst8 + (size_t)row * DD + wv2 * 32 + l15;
            drow[0]  = (signed char)q0;
            drow[16] = (signed char)q1;
            if (wv2 == 0 && l15 == 0) dst_scale[row] = rmax * (1.f / 127.f);
        }
    } else {
        #pragma unroll
        for (int r = 0; r < 4; ++r) {
            const int rl  = quad * 4 + r;
            const int row = row0 + rl;
            if (row >= n) continue;
            float* drow = dst_f32 + (size_t)row * DD + wv2 * 32 + l15;
            drow[0]  = x0[r];
            drow[16] = x1[r];
        }
    }
}

extern "C" void kernel_launch(void* const* d_in, const int* in_sizes, int n_in,
                              void* d_out, int out_size, void* d_ws, size_t ws_size,
                              hipStream_t stream)
{
    const float* node_repr = (const float*)d_in[0];
    const int*   adj       = (const int*)  d_in[1];
    const float* weight    = (const float*)d_in[2];
    const float* mask      = (const float*)d_in[3];
    const float* W_pos     = (const float*)d_in[4];   // [L,128,128]
    const float* W_neg     = (const float*)d_in[5];

    const int n = in_sizes[0] / DD;                   // 50000

    // workspace (~20 MB): q8 | aggP8 | aggN8 | qsc | ascP | ascN | WT
    signed char* q8    = (signed char*)d_ws;                    // n*128 B (x8 then y8)
    signed char* aggP8 = q8 + (size_t)n * DD;                   // n*128 B
    signed char* aggN8 = aggP8 + (size_t)n * DD;                // n*128 B
    float*       qsc   = (float*)(aggN8 + (size_t)n * DD);      // n f32 (xsc then ysc)
    float*       ascP  = qsc + n;                               // n f32
    float*       ascN  = ascP + n;                              // n f32
    _Float16*    WT    = (_Float16*)(ascN + n);                 // 4*128*128 f16

    const int nA = n / 16;                                      // 3125 row-quant blocks
    prep<<<nA + 32, 256, 0, stream>>>(node_repr, mask, q8, qsc, nA,
                                      W_pos, W_neg, WT);

    dim3 grid((n + TM - 1) / TM);
    // layer 0
    gather_agg<<<grid, 256, 0, stream>>>(q8, qsc, adj, weight,
                                         aggP8, aggN8, ascP, ascN, n);
    gemm_ep<<<grid, 256, 0, stream>>>(aggP8, aggN8, ascP, ascN, mask,
                                      WT + 0 * DD * DD, WT + 1 * DD * DD,
                                      nullptr, q8, qsc, n, 1);
    // layer 1 (q8/qsc now hold y)
    gather_agg<<<grid, 256, 0, stream>>>(q8, qsc, adj, weight,
                                         aggP8, aggN8, ascP, ascN, n);
    gemm_ep<<<grid, 256, 0, stream>>>(aggP8, aggN8, ascP, ascN, mask,
                                      WT + 2 * DD * DD, WT + 3 * DD * DD,
                                      (float*)d_out, nullptr, nullptr, n, 0);
}

// Round 9
// 180.858 us; speedup vs baseline: 1.1919x; 1.1919x over previous
//
#include <hip/hip_runtime.h>
#include <math.h>

#define DD 128          // embed dim
#define DEG 16          // neighbors
#define TM 16           // node tile (ntiles = 50000/16 = 3125 exactly)
#define LDST 136        // LDS row stride in f16
#define EPSV 1e-5f
#define PGRID 1024      // persistent blocks for grid-stride kernels (4/CU)

typedef _Float16 half8_t __attribute__((ext_vector_type(8)));
typedef float    f32x4   __attribute__((ext_vector_type(4)));
typedef signed char c16v __attribute__((ext_vector_type(16)));

// fast tanh(n)/n, n >= EPSV.
__device__ __forceinline__ float fast_tanh_over(float n) {
    float e  = __expf(2.f * n);
    float th = 1.f - __fdividef(2.f, e + 1.f);
    return __fdividef(th, n);
}
// fast atanh(n)/n, n in [EPSV, 1-EPSV]
__device__ __forceinline__ float fast_atanh_over(float n) {
    float r = 0.5f * __logf(__fdividef(1.f + n, 1.f - n));
    return __fdividef(r, n);
}

// ---- prep: per-ROW int8 quant of x*mask^2 + W->f16 transpose.
// R9: PERSISTENT grid-stride. R0-R8 showed every ~3125-short-block dispatch
// costs 50-65us regardless of content (prep was ~60us for 38MB streaming);
// blocks doing ~2us of work pay a dominant setup/turnover cost. Amortize it.
__global__ __launch_bounds__(256, 2) void prep(
    const float* __restrict__ x, const float* __restrict__ mask,
    signed char* __restrict__ x8, float* __restrict__ xsc, int nA,
    const float* __restrict__ Wp, const float* __restrict__ Wn,
    _Float16* __restrict__ WT)
{
    if ((int)blockIdx.x < PGRID) {
        const int rr  = threadIdx.x >> 4;
        const int c16 = threadIdx.x & 15;
        for (int tb = blockIdx.x; tb < nA; tb += PGRID) {
            const int r = tb * 16 + rr;
            float m  = mask[r];
            float m2 = m * m;
            const float4* xp = (const float4*)(x + (size_t)r * DD + c16 * 8);
            float4 a = xp[0], b = xp[1];
            float v[8] = {a.x*m2, a.y*m2, a.z*m2, a.w*m2, b.x*m2, b.y*m2, b.z*m2, b.w*m2};
            float mx = 0.f;
            #pragma unroll
            for (int c = 0; c < 8; ++c) mx = fmaxf(mx, fabsf(v[c]));
            mx = fmaxf(mx, __shfl_xor(mx, 1));
            mx = fmaxf(mx, __shfl_xor(mx, 2));
            mx = fmaxf(mx, __shfl_xor(mx, 4));
            mx = fmaxf(mx, __shfl_xor(mx, 8));
            float qs = __fdividef(127.f, fmaxf(mx, 1e-20f));
            int q[8];
            #pragma unroll
            for (int c = 0; c < 8; ++c) q[c] = __float2int_rn(v[c] * qs);
            unsigned lo = (q[0]&255) | ((q[1]&255)<<8) | ((q[2]&255)<<16) | ((unsigned)(q[3]&255)<<24);
            unsigned hi = (q[4]&255) | ((q[5]&255)<<8) | ((q[6]&255)<<16) | ((unsigned)(q[7]&255)<<24);
            *(uint2*)(x8 + (size_t)r * DD + c16 * 8) = make_uint2(lo, hi);
            if (c16 == 0) xsc[r] = mx * (1.f / 127.f);
        }
    } else {
        int bid   = blockIdx.x - PGRID;    // 0..31
        int mat   = bid >> 3;              // 0..3: [l0p, l0n, l1p, l1n]
        int chunk = bid & 7;
        int l = mat >> 1, rel = mat & 1;
        const float* __restrict__ src = (rel ? Wn : Wp) + (size_t)l * DD * DD;
        _Float16* __restrict__ dst = WT + (size_t)mat * DD * DD;
        for (int o = chunk * 2048 + threadIdx.x; o < chunk * 2048 + 2048; o += 256) {
            int nn = o >> 7, kk = o & 127;
            dst[o] = (_Float16)src[kk * DD + nn];   // WT[n][k] (transposed)
        }
    }
}

// ---- one fused GNN layer (R7 body, verified absmax 0.0029), PERSISTENT.
// Each block processes ~3 tiles; block setup/turnover amortized 3x. Same 3
// dispatches as R7 -> clean A/B on grid-striding alone.
__global__ __launch_bounds__(256, 2) void fused_layer(
    const signed char* __restrict__ src8,        // int8, per-row scaled
    const float* __restrict__ sscale,            // per-row scale (rowmax/127)
    const int*   __restrict__ adj, const float* __restrict__ wgt,
    const float* __restrict__ mask,
    const _Float16* __restrict__ WTp, const _Float16* __restrict__ WTn,
    float* __restrict__ dst_f32,
    signed char* __restrict__ dst8, float* __restrict__ dst_scale,
    int n, int apply_logmap)
{
    __shared__ __align__(16) _Float16 aggP[TM][LDST];   // 4.25 KB
    __shared__ __align__(16) _Float16 aggN[TM][LDST];   // 4.25 KB
    __shared__ int   eidxS[TM][DEG];                     // 1 KB
    __shared__ float ewgtS[TM][DEG];                     // 1 KB
    __shared__ float msh[TM];
    __shared__ float partA[4][TM];
    __shared__ float partB[4][TM];
    __shared__ float partC[4][TM];

    const int tid   = threadIdx.x;
    const int ntile = (n + TM - 1) / TM;

    for (int tile = blockIdx.x; tile < ntile; tile += gridDim.x) {
        const int row0 = tile * TM;

        // ---- phase 0: stage adjacency, folded weights, mask ----
        {
            const int nd = tid >> 4, eg = tid & 15;
            int   av = adj[(size_t)(row0 + nd) * DEG + eg];
            float wv = wgt[(size_t)(row0 + nd) * DEG + eg];
            eidxS[nd][eg] = av;
            ewgtS[nd][eg] = wv * sscale[av];
            if (tid < TM) msh[tid] = mask[row0 + tid];
        }
        __syncthreads();

        // ---- phase 1: gather-aggregate. 8 dwordx4 int8 gathers/wave ----
        const int l64  = tid & 63;
        const int node = (tid >> 6) * 4 + (l64 >> 4);   // 4 nodes per wave
        const int e    = (l64 >> 3) & 1;                // edge parity
        const int g    = l64 & 7;                       // 16-byte column group

        int   idxl[8];
        float wl[8];
        #pragma unroll
        for (int j = 0; j < 8; ++j) {
            idxl[j] = eidxS[node][2 * j + e];
            wl[j]   = ewgtS[node][2 * j + e];
        }

        float aP[16], aN[16];
        #pragma unroll
        for (int c = 0; c < 16; ++c) { aP[c] = 0.f; aN[c] = 0.f; }
        const signed char* __restrict__ srcg = src8 + g * 16;
        #pragma unroll
        for (int j = 0; j < 8; ++j) {
            c16v v = *(const c16v*)(srcg + ((size_t)idxl[j] << 7));
            float wp = fmaxf(wl[j], 0.f);
            float wn = fmaxf(-wl[j], 0.f);
            #pragma unroll
            for (int c = 0; c < 16; ++c) {
                float f = (float)v[c];
                aP[c] += wp * f;
                aN[c] += wn * f;
            }
        }
        // parity merge (R7-verified): keep own half, send opposite half
        {
            half8_t hP, hN;
            #pragma unroll
            for (int c = 0; c < 8; ++c) {
                float ownP  = e ? aP[8 + c] : aP[c];
                float sendP = e ? aP[c]     : aP[8 + c];
                float ownN  = e ? aN[8 + c] : aN[c];
                float sendN = e ? aN[c]     : aN[8 + c];
                hP[c] = (_Float16)(ownP + __shfl_xor(sendP, 8));
                hN[c] = (_Float16)(ownN + __shfl_xor(sendN, 8));
            }
            *(half8_t*)&aggP[node][g * 16 + e * 8] = hP;
            *(half8_t*)&aggN[node][g * 16 + e * 8] = hN;
        }
        __syncthreads();

        // ---- phase 2: MFMA. 4 waves split the 8 n-blocks (2 each) ----
        const int wv2  = tid >> 6;
        const int l15  = l64 & 15;
        const int quad = l64 >> 4;

        half8_t aPf[4], aNf[4];
        #pragma unroll
        for (int kb = 0; kb < 4; ++kb) {
            aPf[kb] = *(const half8_t*)&aggP[l15][kb * 32 + quad * 8];
            aNf[kb] = *(const half8_t*)&aggN[l15][kb * 32 + quad * 8];
        }

        f32x4 acc[2];
        acc[0] = (f32x4){0.f, 0.f, 0.f, 0.f};
        acc[1] = (f32x4){0.f, 0.f, 0.f, 0.f};
        #pragma unroll
        for (int t = 0; t < 2; ++t) {
            const int nb = wv2 * 2 + t;
            const _Float16* bp = WTp + (size_t)(nb * 16 + l15) * DD + quad * 8;
            const _Float16* bn = WTn + (size_t)(nb * 16 + l15) * DD + quad * 8;
            #pragma unroll
            for (int kb = 0; kb < 4; ++kb) {
                acc[t] = __builtin_amdgcn_mfma_f32_16x16x32_f16(
                    aPf[kb], *(const half8_t*)(bp + kb * 32), acc[t], 0, 0, 0);
                acc[t] = __builtin_amdgcn_mfma_f32_16x16x32_f16(
                    aNf[kb], *(const half8_t*)(bn + kb * 32), acc[t], 0, 0, 0);
            }
        }

        // ---- phase 3: epilogue ----
        float cv0[4], cv1[4], mr[4];
        #pragma unroll
        for (int r = 0; r < 4; ++r) {
            const int rl  = quad * 4 + r;
            const int row = row0 + rl;
            float m = (row < n) ? msh[rl] : 0.f;
            mr[r] = m;
            float c0 = acc[0][r] * m, c1 = acc[1][r] * m;
            cv0[r] = c0; cv1[r] = c1;
            float p = c0 * c0 + c1 * c1;
            p += __shfl_xor(p, 1); p += __shfl_xor(p, 2);
            p += __shfl_xor(p, 4); p += __shfl_xor(p, 8);
            if (l15 == 0) partA[wv2][rl] = p;
        }
        __syncthreads();

        float x0[4], x1[4];
        #pragma unroll
        for (int r = 0; r < 4; ++r) {
            const int rl = quad * 4 + r;
            float c2 = partA[0][rl] + partA[1][rl] + partA[2][rl] + partA[3][rl];
            float nc = fmaxf(sqrtf(c2), EPSV);
            float sc = fast_tanh_over(nc);
            float m  = mr[r];
            float t0 = fmaxf(cv0[r] * sc * m, 0.f) * m;
            float t1 = fmaxf(cv1[r] * sc * m, 0.f) * m;
            x0[r] = t0; x1[r] = t1;
            if (apply_logmap) {
                float p = t0 * t0 + t1 * t1;
                p += __shfl_xor(p, 1); p += __shfl_xor(p, 2);
                p += __shfl_xor(p, 4); p += __shfl_xor(p, 8);
                if (l15 == 0) partB[wv2][rl] = p;
            }
        }

        if (apply_logmap) {
            __syncthreads();
            float y0r[4], y1r[4];
            #pragma unroll
            for (int r = 0; r < 4; ++r) {
                const int rl = quad * 4 + r;
                float s2  = partB[0][rl] + partB[1][rl] + partB[2][rl] + partB[3][rl];
                float nc2 = fminf(fmaxf(sqrtf(s2), EPSV), 1.f - EPSV);
                float f = fast_atanh_over(nc2) * mr[r] * mr[r];
                float y0 = x0[r] * f, y1 = x1[r] * f;
                y0r[r] = y0; y1r[r] = y1;
                float mm = fmaxf(fabsf(y0), fabsf(y1));
                mm = fmaxf(mm, __shfl_xor(mm, 1));
                mm = fmaxf(mm, __shfl_xor(mm, 2));
                mm = fmaxf(mm, __shfl_xor(mm, 4));
                mm = fmaxf(mm, __shfl_xor(mm, 8));
                if (l15 == 0) partC[wv2][rl] = mm;
            }
            __syncthreads();
            #pragma unroll
            for (int r = 0; r < 4; ++r) {
                const int rl  = quad * 4 + r;
                const int row = row0 + rl;
                if (row >= n) continue;
                float rmax = fmaxf(fmaxf(partC[0][rl], partC[1][rl]),
                                   fmaxf(partC[2][rl], partC[3][rl]));
                float qs = __fdividef(127.f, fmaxf(rmax, 1e-20f));
                int q0 = __float2int_rn(y0r[r] * qs);
                int q1 = __float2int_rn(y1r[r] * qs);
                signed char* drow = dst8 + (size_t)row * DD + wv2 * 32 + l15;
                drow[0]  = (signed char)q0;
                drow[16] = (signed char)q1;
                if (wv2 == 0 && l15 == 0) dst_scale[row] = rmax * (1.f / 127.f);
            }
        } else {
            #pragma unroll
            for (int r = 0; r < 4; ++r) {
                const int rl  = quad * 4 + r;
                const int row = row0 + rl;
                if (row >= n) continue;
                float* drow = dst_f32 + (size_t)row * DD + wv2 * 32 + l15;
                drow[0]  = x0[r];
                drow[16] = x1[r];
            }
        }
        __syncthreads();   // defensive: LDS reuse across tile iterations
    }
}

extern "C" void kernel_launch(void* const* d_in, const int* in_sizes, int n_in,
                              void* d_out, int out_size, void* d_ws, size_t ws_size,
                              hipStream_t stream)
{
    const float* node_repr = (const float*)d_in[0];
    const int*   adj       = (const int*)  d_in[1];
    const float* weight    = (const float*)d_in[2];
    const float* mask      = (const float*)d_in[3];
    const float* W_pos     = (const float*)d_in[4];   // [L,128,128]
    const float* W_neg     = (const float*)d_in[5];

    const int n = in_sizes[0] / DD;                   // 50000

    // workspace: x8 | y8 | xsc | ysc | WT
    signed char* x8  = (signed char*)d_ws;                 // n*128 B
    signed char* y8  = x8 + (size_t)n * DD;                // n*128 B
    float*       xsc = (float*)(y8 + (size_t)n * DD);      // n f32
    float*       ysc = xsc + n;                            // n f32
    _Float16*    WT  = (_Float16*)(ysc + n);               // 4*128*128 f16

    const int nA = n / 16;                                 // 3125 row-quant tiles
    prep<<<PGRID + 32, 256, 0, stream>>>(node_repr, mask, x8, xsc, nA,
                                         W_pos, W_neg, WT);

    // persistent fused layers: 1024 blocks, ~3.05 tiles each
    fused_layer<<<PGRID, 256, 0, stream>>>(x8, xsc, adj, weight, mask,
                                           WT + 0 * DD * DD, WT + 1 * DD * DD,
                                           nullptr, y8, ysc, n, 1);
    fused_layer<<<PGRID, 256, 0, stream>>>(y8, ysc, adj, weight, mask,
                                           WT + 2 * DD * DD, WT + 3 * DD * DD,
                                           (float*)d_out, nullptr, nullptr, n, 0);
}

// Round 10
// 180.720 us; speedup vs baseline: 1.1929x; 1.0008x over previous
//
#include <hip/hip_runtime.h>
#include <math.h>

#define DD 128          // embed dim
#define DEG 16          // neighbors
#define TM 16           // node tile per block (grid = 50000/16 = 3125 exactly)
#define LDST 136        // LDS row stride in f16
#define EPSV 1e-5f
#define PGRID 1024      // persistent blocks for the streaming prep kernel

typedef _Float16 half8_t __attribute__((ext_vector_type(8)));
typedef float    f32x4   __attribute__((ext_vector_type(4)));
typedef signed char c16v __attribute__((ext_vector_type(16)));

// fast tanh(n)/n, n >= EPSV.
__device__ __forceinline__ float fast_tanh_over(float n) {
    float e  = __expf(2.f * n);
    float th = 1.f - __fdividef(2.f, e + 1.f);
    return __fdividef(th, n);
}
// fast atanh(n)/n, n in [EPSV, 1-EPSV]
__device__ __forceinline__ float fast_atanh_over(float n) {
    float r = 0.5f * __logf(__fdividef(1.f + n, 1.f - n));
    return __fdividef(r, n);
}

// ---- prep: PERSISTENT grid-stride (R9-measured ~32us vs ~65us short-block).
// Per-row int8 quant of x*mask^2 + W->f16 transpose.
__global__ __launch_bounds__(256, 2) void prep(
    const float* __restrict__ x, const float* __restrict__ mask,
    signed char* __restrict__ x8, float* __restrict__ xsc, int nA,
    const float* __restrict__ Wp, const float* __restrict__ Wn,
    _Float16* __restrict__ WT)
{
    if ((int)blockIdx.x < PGRID) {
        const int rr  = threadIdx.x >> 4;
        const int c16 = threadIdx.x & 15;
        for (int tb = blockIdx.x; tb < nA; tb += PGRID) {
            const int r = tb * 16 + rr;
            float m  = mask[r];
            float m2 = m * m;
            const float4* xp = (const float4*)(x + (size_t)r * DD + c16 * 8);
            float4 a = xp[0], b = xp[1];
            float v[8] = {a.x*m2, a.y*m2, a.z*m2, a.w*m2, b.x*m2, b.y*m2, b.z*m2, b.w*m2};
            float mx = 0.f;
            #pragma unroll
            for (int c = 0; c < 8; ++c) mx = fmaxf(mx, fabsf(v[c]));
            mx = fmaxf(mx, __shfl_xor(mx, 1));
            mx = fmaxf(mx, __shfl_xor(mx, 2));
            mx = fmaxf(mx, __shfl_xor(mx, 4));
            mx = fmaxf(mx, __shfl_xor(mx, 8));
            float qs = __fdividef(127.f, fmaxf(mx, 1e-20f));
            int q[8];
            #pragma unroll
            for (int c = 0; c < 8; ++c) q[c] = __float2int_rn(v[c] * qs);
            unsigned lo = (q[0]&255) | ((q[1]&255)<<8) | ((q[2]&255)<<16) | ((unsigned)(q[3]&255)<<24);
            unsigned hi = (q[4]&255) | ((q[5]&255)<<8) | ((q[6]&255)<<16) | ((unsigned)(q[7]&255)<<24);
            *(uint2*)(x8 + (size_t)r * DD + c16 * 8) = make_uint2(lo, hi);
            if (c16 == 0) xsc[r] = mx * (1.f / 127.f);
        }
    } else {
        int bid   = blockIdx.x - PGRID;    // 0..31
        int mat   = bid >> 3;              // 0..3: [l0p, l0n, l1p, l1n]
        int chunk = bid & 7;
        int l = mat >> 1, rel = mat & 1;
        const float* __restrict__ src = (rel ? Wn : Wp) + (size_t)l * DD * DD;
        _Float16* __restrict__ dst = WT + (size_t)mat * DD * DD;
        for (int o = chunk * 2048 + threadIdx.x; o < chunk * 2048 + 2048; o += 256) {
            int nn = o >> 7, kk = o & 127;
            dst[o] = (_Float16)src[kk * DD + nn];   // WT[n][k] (transposed)
        }
    }
}

// ---- one fused GNN layer: EXACT R7 body (57.5us/layer, VGPR 72, absmax
// 0.0029). NON-persistent 3125-block launch: R9 proved the persistent tile
// loop bloats live state (VGPR 72->120, occ 27->20%, dur +30%) -- turnover
// amortization helps streaming kernels (prep) but loses on this one.
__global__ __launch_bounds__(256, 2) void fused_layer(
    const signed char* __restrict__ src8,        // int8, per-row scaled
    const float* __restrict__ sscale,            // per-row scale (rowmax/127)
    const int*   __restrict__ adj, const float* __restrict__ wgt,
    const float* __restrict__ mask,
    const _Float16* __restrict__ WTp, const _Float16* __restrict__ WTn,
    float* __restrict__ dst_f32,
    signed char* __restrict__ dst8, float* __restrict__ dst_scale,
    int n, int apply_logmap)
{
    __shared__ __align__(16) _Float16 aggP[TM][LDST];   // 4.25 KB
    __shared__ __align__(16) _Float16 aggN[TM][LDST];   // 4.25 KB
    __shared__ int   eidxS[TM][DEG];                     // 1 KB
    __shared__ float ewgtS[TM][DEG];                     // 1 KB (weight * src row-scale)
    __shared__ float msh[TM];
    __shared__ float partA[4][TM];
    __shared__ float partB[4][TM];
    __shared__ float partC[4][TM];

    const int row0 = blockIdx.x * TM;
    const int tid  = threadIdx.x;

    // ---- phase 0: stage adjacency, folded weights, mask (1 dword/thread) ----
    {
        const int nd = tid >> 4, eg = tid & 15;
        int   av = adj[(size_t)(row0 + nd) * DEG + eg];
        float wv = wgt[(size_t)(row0 + nd) * DEG + eg];
        float sv = sscale[av];                 // per-edge source row scale (>=0)
        eidxS[nd][eg] = av;
        ewgtS[nd][eg] = wv * sv;               // sign preserved -> pos/neg split ok
        if (tid < TM) msh[tid] = mask[row0 + tid];
    }
    __syncthreads();

    // ---- phase 1: gather-aggregate. 8 dwordx4 gathers/wave (8 lanes/row) ----
    const int l64  = tid & 63;
    const int node = (tid >> 6) * 4 + (l64 >> 4);   // 4 nodes per wave
    const int e    = (l64 >> 3) & 1;                // edge parity within instr
    const int g    = l64 & 7;                       // 16-byte column group

    int   idxl[8];
    float wl[8];
    #pragma unroll
    for (int j = 0; j < 8; ++j) {
        idxl[j] = eidxS[node][2 * j + e];
        wl[j]   = ewgtS[node][2 * j + e];
    }

    float aP[16], aN[16];
    #pragma unroll
    for (int c = 0; c < 16; ++c) { aP[c] = 0.f; aN[c] = 0.f; }
    const signed char* __restrict__ srcg = src8 + g * 16;
    #pragma unroll
    for (int j = 0; j < 8; ++j) {
        c16v v = *(const c16v*)(srcg + ((size_t)idxl[j] << 7));
        float wp = fmaxf(wl[j], 0.f);
        float wn = fmaxf(-wl[j], 0.f);
        #pragma unroll
        for (int c = 0; c < 16; ++c) {
            float f = (float)v[c];
            aP[c] += wp * f;
            aN[c] += wn * f;
        }
    }
    // merge edge parities: lane^8 covers the SAME 16 columns, other parity.
    // Each lane keeps its own half and SENDS the opposite half (R7-verified).
    {
        half8_t hP, hN;
        #pragma unroll
        for (int c = 0; c < 8; ++c) {
            float ownP  = e ? aP[8 + c] : aP[c];
            float sendP = e ? aP[c]     : aP[8 + c];
            float ownN  = e ? aN[8 + c] : aN[c];
            float sendN = e ? aN[c]     : aN[8 + c];
            hP[c] = (_Float16)(ownP + __shfl_xor(sendP, 8));
            hN[c] = (_Float16)(ownN + __shfl_xor(sendN, 8));
        }
        *(half8_t*)&aggP[node][g * 16 + e * 8] = hP;
        *(half8_t*)&aggN[node][g * 16 + e * 8] = hN;
    }
    __syncthreads();

    // ---- phase 2: MFMA. 4 waves split the 8 n-blocks (2 each); rows shared ----
    const int wv2  = tid >> 6;       // wave 0..3
    const int l15  = l64 & 15;
    const int quad = l64 >> 4;

    half8_t aPf[4], aNf[4];          // A[m=l15][k=kb*32+quad*8+j]
    #pragma unroll
    for (int kb = 0; kb < 4; ++kb) {
        aPf[kb] = *(const half8_t*)&aggP[l15][kb * 32 + quad * 8];
        aNf[kb] = *(const half8_t*)&aggN[l15][kb * 32 + quad * 8];
    }

    f32x4 acc[2];
    acc[0] = (f32x4){0.f, 0.f, 0.f, 0.f};
    acc[1] = (f32x4){0.f, 0.f, 0.f, 0.f};
    #pragma unroll
    for (int t = 0; t < 2; ++t) {
        const int nb = wv2 * 2 + t;
        const _Float16* bp = WTp + (size_t)(nb * 16 + l15) * DD + quad * 8;
        const _Float16* bn = WTn + (size_t)(nb * 16 + l15) * DD + quad * 8;
        #pragma unroll
        for (int kb = 0; kb < 4; ++kb) {
            acc[t] = __builtin_amdgcn_mfma_f32_16x16x32_f16(
                aPf[kb], *(const half8_t*)(bp + kb * 32), acc[t], 0, 0, 0);
            acc[t] = __builtin_amdgcn_mfma_f32_16x16x32_f16(
                aNf[kb], *(const half8_t*)(bn + kb * 32), acc[t], 0, 0, 0);
        }
    }

    // ---- phase 3: epilogue. C/D: row=quad*4+r, cols wv2*32 + {l15, 16+l15} ----
    float cv0[4], cv1[4], mr[4];
    #pragma unroll
    for (int r = 0; r < 4; ++r) {
        const int rl  = quad * 4 + r;
        const int row = row0 + rl;
        float m = (row < n) ? msh[rl] : 0.f;
        mr[r] = m;
        float c0 = acc[0][r] * m, c1 = acc[1][r] * m;
        cv0[r] = c0; cv1[r] = c1;
        float p = c0 * c0 + c1 * c1;
        p += __shfl_xor(p, 1); p += __shfl_xor(p, 2);
        p += __shfl_xor(p, 4); p += __shfl_xor(p, 8);   // within 16-lane group
        if (l15 == 0) partA[wv2][rl] = p;
    }
    __syncthreads();

    float x0[4], x1[4];
    #pragma unroll
    for (int r = 0; r < 4; ++r) {
        const int rl = quad * 4 + r;
        float c2 = partA[0][rl] + partA[1][rl] + partA[2][rl] + partA[3][rl];
        float nc = fmaxf(sqrtf(c2), EPSV);
        float sc = fast_tanh_over(nc);
        float m  = mr[r];
        float t0 = fmaxf(cv0[r] * sc * m, 0.f) * m;      // expmap*m, relu, *m
        float t1 = fmaxf(cv1[r] * sc * m, 0.f) * m;
        x0[r] = t0; x1[r] = t1;
        if (apply_logmap) {                               // uniform branch
            float p = t0 * t0 + t1 * t1;
            p += __shfl_xor(p, 1); p += __shfl_xor(p, 2);
            p += __shfl_xor(p, 4); p += __shfl_xor(p, 8);
            if (l15 == 0) partB[wv2][rl] = p;
        }
    }

    if (apply_logmap) {
        __syncthreads();
        // y = logmap(x)*mask^2; compute + per-row max partials
        float y0r[4], y1r[4];
        #pragma unroll
        for (int r = 0; r < 4; ++r) {
            const int rl = quad * 4 + r;
            float s2  = partB[0][rl] + partB[1][rl] + partB[2][rl] + partB[3][rl];
            float nc2 = fminf(fmaxf(sqrtf(s2), EPSV), 1.f - EPSV);
            float f = fast_atanh_over(nc2) * mr[r] * mr[r];
            float y0 = x0[r] * f, y1 = x1[r] * f;
            y0r[r] = y0; y1r[r] = y1;
            float mm = fmaxf(fabsf(y0), fabsf(y1));
            mm = fmaxf(mm, __shfl_xor(mm, 1));
            mm = fmaxf(mm, __shfl_xor(mm, 2));
            mm = fmaxf(mm, __shfl_xor(mm, 4));
            mm = fmaxf(mm, __shfl_xor(mm, 8));
            if (l15 == 0) partC[wv2][rl] = mm;
        }
        __syncthreads();
        #pragma unroll
        for (int r = 0; r < 4; ++r) {
            const int rl  = quad * 4 + r;
            const int row = row0 + rl;
            if (row >= n) continue;
            float rmax = fmaxf(fmaxf(partC[0][rl], partC[1][rl]),
                               fmaxf(partC[2][rl], partC[3][rl]));
            float qs = __fdividef(127.f, fmaxf(rmax, 1e-20f));
            int q0 = __float2int_rn(y0r[r] * qs);
            int q1 = __float2int_rn(y1r[r] * qs);
            signed char* drow = dst8 + (size_t)row * DD + wv2 * 32 + l15;
            drow[0]  = (signed char)q0;
            drow[16] = (signed char)q1;
            if (wv2 == 0 && l15 == 0) dst_scale[row] = rmax * (1.f / 127.f);
        }
    } else {
        #pragma unroll
        for (int r = 0; r < 4; ++r) {
            const int rl  = quad * 4 + r;
            const int row = row0 + rl;
            if (row >= n) continue;
            float* drow = dst_f32 + (size_t)row * DD + wv2 * 32 + l15;
            drow[0]  = x0[r];
            drow[16] = x1[r];
        }
    }
}

extern "C" void kernel_launch(void* const* d_in, const int* in_sizes, int n_in,
                              void* d_out, int out_size, void* d_ws, size_t ws_size,
                              hipStream_t stream)
{
    const float* node_repr = (const float*)d_in[0];
    const int*   adj       = (const int*)  d_in[1];
    const float* weight    = (const float*)d_in[2];
    const float* mask      = (const float*)d_in[3];
    const float* W_pos     = (const float*)d_in[4];   // [L,128,128]
    const float* W_neg     = (const float*)d_in[5];

    const int n = in_sizes[0] / DD;                   // 50000

    // workspace: x8 | y8 | xsc | ysc | WT
    signed char* x8  = (signed char*)d_ws;                 // n*128 B
    signed char* y8  = x8 + (size_t)n * DD;                // n*128 B
    float*       xsc = (float*)(y8 + (size_t)n * DD);      // n f32
    float*       ysc = xsc + n;                            // n f32
    _Float16*    WT  = (_Float16*)(ysc + n);               // 4*128*128 f16

    const int nA = n / 16;                                 // 3125 row-quant tiles
    prep<<<PGRID + 32, 256, 0, stream>>>(node_repr, mask, x8, xsc, nA,
                                         W_pos, W_neg, WT);

    dim3 grid((n + TM - 1) / TM);                          // 3125 blocks of 256
    // layer 0: gather x8, write y8 (int8 row-scaled) + ysc
    fused_layer<<<grid, 256, 0, stream>>>(x8, xsc, adj, weight, mask,
                                          WT + 0 * DD * DD, WT + 1 * DD * DD,
                                          nullptr, y8, ysc, n, 1);
    // layer 1: gather y8, write f32 output
    fused_layer<<<grid, 256, 0, stream>>>(y8, ysc, adj, weight, mask,
                                          WT + 2 * DD * DD, WT + 3 * DD * DD,
                                          (float*)d_out, nullptr, nullptr, n, 0);
}